// Round 4
// baseline (2256.958 us; speedup 1.0000x reference)
//
#include <hip/hip_runtime.h>
#include <math.h>

#define B_ 32
#define T_ 512
#define I_ 512
#define H_ 1024
#define O_ 512
#define MT (B_*T_)   // 16384 rows

// Per-block ready flags: 8 bg-groups x 32 js-blocks. flag[bg][js] = t means
// block (bg,js) has completed step t-1's h stores (visible at L3).
// Zeroed by phase-1 GEMM block (0,0) with sc0sc1 stores each replay.
__device__ unsigned g_cnt[256];

// ---------------------------------------------------------------------------
// GEMM: C[m][n] = bias[n] + sum_k A[m][k] * Bm[n][k]   (both row-major, "NT")
// ---------------------------------------------------------------------------
__global__ __launch_bounds__(256)
void gemm_nt_bias(float* __restrict__ C, const float* __restrict__ A,
                  const float* __restrict__ Bm, const float* __restrict__ bias,
                  int M, int N, int K, unsigned* __restrict__ cnt) {
  __shared__ float As[16][132];
  __shared__ float Bs[16][132];
  const int tid = threadIdx.x;
  if (cnt != nullptr && blockIdx.x == 0 && blockIdx.y == 0) {
    // sc0sc1 so the cooperative kernel's L2-bypass polls see the zeros
    asm volatile("global_store_dword %0, %1, off sc0 sc1"
                 :: "v"(cnt + tid), "v"(0u) : "memory");
  }
  const int bm = blockIdx.x * 128;
  const int bn = blockIdx.y * 128;
  const int lr = tid >> 2;
  const int lc = (tid & 3) * 4;
  const int tm = (tid >> 4) * 8;
  const int tn = (tid & 15) * 8;

  float acc[8][8];
#pragma unroll
  for (int i = 0; i < 8; ++i)
#pragma unroll
    for (int j = 0; j < 8; ++j) acc[i][j] = 0.f;

  for (int k0 = 0; k0 < K; k0 += 16) {
    float4 a0 = *(const float4*)(A  + (size_t)(bm + lr)      * K + k0 + lc);
    float4 a1 = *(const float4*)(A  + (size_t)(bm + lr + 64) * K + k0 + lc);
    float4 b0 = *(const float4*)(Bm + (size_t)(bn + lr)      * K + k0 + lc);
    float4 b1 = *(const float4*)(Bm + (size_t)(bn + lr + 64) * K + k0 + lc);
    __syncthreads();
    As[lc+0][lr]    = a0.x; As[lc+1][lr]    = a0.y; As[lc+2][lr]    = a0.z; As[lc+3][lr]    = a0.w;
    As[lc+0][lr+64] = a1.x; As[lc+1][lr+64] = a1.y; As[lc+2][lr+64] = a1.z; As[lc+3][lr+64] = a1.w;
    Bs[lc+0][lr]    = b0.x; Bs[lc+1][lr]    = b0.y; Bs[lc+2][lr]    = b0.z; Bs[lc+3][lr]    = b0.w;
    Bs[lc+0][lr+64] = b1.x; Bs[lc+1][lr+64] = b1.y; Bs[lc+2][lr+64] = b1.z; Bs[lc+3][lr+64] = b1.w;
    __syncthreads();
#pragma unroll
    for (int k = 0; k < 16; ++k) {
      float a[8], b[8];
      *(float4*)&a[0] = *(const float4*)&As[k][tm];
      *(float4*)&a[4] = *(const float4*)&As[k][tm + 4];
      *(float4*)&b[0] = *(const float4*)&Bs[k][tn];
      *(float4*)&b[4] = *(const float4*)&Bs[k][tn + 4];
#pragma unroll
      for (int i = 0; i < 8; ++i)
#pragma unroll
        for (int j = 0; j < 8; ++j) acc[i][j] += a[i] * b[j];
    }
  }

  float bv[8];
#pragma unroll
  for (int j = 0; j < 8; ++j) bv[j] = bias[bn + tn + j];
#pragma unroll
  for (int i = 0; i < 8; ++i) {
    float* crow = C + (size_t)(bm + tm + i) * N + bn + tn;
    float4 o0 = {acc[i][0]+bv[0], acc[i][1]+bv[1], acc[i][2]+bv[2], acc[i][3]+bv[3]};
    float4 o1 = {acc[i][4]+bv[4], acc[i][5]+bv[5], acc[i][6]+bv[6], acc[i][7]+bv[7]};
    *(float4*)(crow)     = o0;
    *(float4*)(crow + 4) = o1;
  }
}

// ---------------------------------------------------------------------------
// Fused recurrence, all 512 steps, one cooperative launch.
// h exchange via sc0sc1 (L1/L2-bypass -> coherent L3). Sync via 32 per-block
// flags per bg-group: producer does ONE plain flag store (no RMW, no hot-line
// serialization); every wave polls all 32 flags in parallel and exits
// independently (no post-poll barrier needed). pre-load issued before the
// poll so its latency hides under the wait.
// ---------------------------------------------------------------------------
__global__ __launch_bounds__(512, 2)
void rnn_fused(float* __restrict__ z, const float* __restrict__ h0,
               const float* __restrict__ Whh, const float* __restrict__ bhh,
               unsigned* __restrict__ cnt) {
  __shared__ float hs[4][1024];    // 16 KB: h_{t-1} tile

  const int tid = threadIdx.x;
  const int bg  = blockIdx.x & 7;
  const int js  = blockIdx.x >> 3;
  const int j0  = js * 32;
  const int b0  = bg * 4;
  unsigned* gflags = cnt + bg * 32;

  const int jg   = tid >> 6;       // 0..7
  const int ksl  = tid & 63;       // 64-way k split
  const int w    = ksl >> 2;       // output idx this lane holds post-reduce
  const int jj   = w >> 2;         // 0..3
  const int bb   = w & 3;          // 0..3
  const int srow = tid >> 7;       // 0..3 staging row
  const int sc   = tid & 127;      // staging float4 col
  const int pl   = tid & 31;       // flag index this lane polls
  const bool own = (pl == js);     // own flag: already drained locally

  // ---- W slice into registers (constant across all 512 steps) ----
  float4 wr[4][4];
#pragma unroll
  for (int kc = 0; kc < 4; ++kc)
#pragma unroll
    for (int j = 0; j < 4; ++j)
      wr[kc][j] = *(const float4*)(Whh + (size_t)(j0 + jg*4 + j) * H_ + ksl*4 + kc*256);

  const float breg = bhh[j0 + jg*4 + jj];

  for (int t = 0; t < T_; ++t) {
    const float* zpre = z + ((size_t)(b0 + bb) * T_ + t) * H_ + j0 + jg*4 + jj;
    float pre;

    if (t) {
      __syncthreads();             // whole block's step t-1 stores drained
      if (tid == 0)
        asm volatile("global_store_dword %0, %1, off sc0 sc1"
                     :: "v"(gflags + js), "v"((unsigned)t) : "memory");
      // issue pre load now: latency hides under the flag poll
      asm volatile("global_load_dword %0, %1, off"
                   : "=v"(pre) : "v"(zpre) : "memory");
      // poll all 32 group flags in parallel (2 lanes per flag)
      unsigned fv;
      do {
        asm volatile("global_load_dword %0, %1, off sc0 sc1\n\t"
                     "s_waitcnt vmcnt(0)"
                     : "=v"(fv) : "v"(gflags + pl) : "memory");
      } while (!__all(own || fv >= (unsigned)t));
    } else {
      asm volatile("global_load_dword %0, %1, off"
                   : "=v"(pre) : "v"(zpre) : "memory");
    }

    // ---- stage h_{t-1}[b0..b0+3][:] (16 KB, L2-bypass loads) ----
    const float* hrow = (t == 0)
        ? (h0 + (size_t)(b0 + srow) * H_ + sc * 4)
        : (z + ((size_t)(b0 + srow) * T_ + (t - 1)) * H_ + sc * 4);
    float4 ha, hb;
    asm volatile(
      "global_load_dwordx4 %0, %2, off sc0 sc1\n\t"
      "global_load_dwordx4 %1, %2, off offset:2048 sc0 sc1\n\t"
      "s_waitcnt vmcnt(0)"
      : "=&v"(ha), "=&v"(hb)
      : "v"(hrow)
      : "memory");
    *(float4*)&hs[srow][sc * 4]       = ha;
    *(float4*)&hs[srow][sc * 4 + 512] = hb;
    __syncthreads();

    // ---- 4j x 4b microtile over this lane's 4 float4 k-chunks ----
    float acc[16];
#pragma unroll
    for (int m = 0; m < 16; ++m) acc[m] = 0.f;
#pragma unroll
    for (int kc = 0; kc < 4; ++kc) {
      const int k = ksl * 4 + kc * 256;
      float4 h0v = *(const float4*)&hs[0][k];
      float4 h1v = *(const float4*)&hs[1][k];
      float4 h2v = *(const float4*)&hs[2][k];
      float4 h3v = *(const float4*)&hs[3][k];
#pragma unroll
      for (int j = 0; j < 4; ++j) {
        float4 wv = wr[kc][j];
        acc[j*4+0] += wv.x*h0v.x + wv.y*h0v.y + wv.z*h0v.z + wv.w*h0v.w;
        acc[j*4+1] += wv.x*h1v.x + wv.y*h1v.y + wv.z*h1v.z + wv.w*h1v.w;
        acc[j*4+2] += wv.x*h2v.x + wv.y*h2v.y + wv.z*h2v.z + wv.w*h2v.w;
        acc[j*4+3] += wv.x*h3v.x + wv.y*h3v.y + wv.z*h3v.z + wv.w*h3v.w;
      }
    }

    // ---- packing reduction over 64 lanes: 17 shuffles, value w -> lane 4w ----
    const bool b5 = (ksl & 32) != 0;
    float r8[8];
#pragma unroll
    for (int m = 0; m < 8; ++m) {
      float keep = b5 ? acc[m+8] : acc[m];
      float send = b5 ? acc[m]   : acc[m+8];
      r8[m] = keep + __shfl_xor(send, 32, 64);
    }
    const bool b4 = (ksl & 16) != 0;
    float r4[4];
#pragma unroll
    for (int m = 0; m < 4; ++m) {
      float keep = b4 ? r8[m+4] : r8[m];
      float send = b4 ? r8[m]   : r8[m+4];
      r4[m] = keep + __shfl_xor(send, 16, 64);
    }
    const bool b3 = (ksl & 8) != 0;
    float r2[2];
#pragma unroll
    for (int m = 0; m < 2; ++m) {
      float keep = b3 ? r4[m+2] : r4[m];
      float send = b3 ? r4[m]   : r4[m+2];
      r2[m] = keep + __shfl_xor(send, 8, 64);
    }
    const bool b2 = (ksl & 4) != 0;
    float r1 = (b2 ? r2[1] : r2[0]) + __shfl_xor(b2 ? r2[0] : r2[1], 4, 64);
    r1 += __shfl_xor(r1, 2, 64);
    r1 += __shfl_xor(r1, 1, 64);
    // lane 4w now holds the full k-sum of output w = jj*4+bb

    if ((ksl & 3) == 0) {
      float v = tanhf(r1 + pre + breg);
      asm volatile("global_store_dword %0, %1, off sc0 sc1"
                   :: "v"(zpre), "v"(v) : "memory");
    }
    asm volatile("s_waitcnt vmcnt(0)" ::: "memory");  // own stores drained
  }
}

// ---------------------------------------------------------------------------
// Row softmax in place over O_=512 columns. One wave per row.
// ---------------------------------------------------------------------------
__global__ __launch_bounds__(256)
void softmax_rows(float* __restrict__ P) {
  const int row  = blockIdx.x * 4 + (threadIdx.x >> 6);
  const int lane = threadIdx.x & 63;
  float* p = P + (size_t)row * O_;
  float4 v0 = *(const float4*)(p + lane * 4);
  float4 v1 = *(const float4*)(p + 256 + lane * 4);

  float m = fmaxf(fmaxf(fmaxf(v0.x, v0.y), fmaxf(v0.z, v0.w)),
                  fmaxf(fmaxf(v1.x, v1.y), fmaxf(v1.z, v1.w)));
#pragma unroll
  for (int off = 32; off; off >>= 1) m = fmaxf(m, __shfl_xor(m, off, 64));

  v0.x = __expf(v0.x - m); v0.y = __expf(v0.y - m);
  v0.z = __expf(v0.z - m); v0.w = __expf(v0.w - m);
  v1.x = __expf(v1.x - m); v1.y = __expf(v1.y - m);
  v1.z = __expf(v1.z - m); v1.w = __expf(v1.w - m);

  float s = v0.x + v0.y + v0.z + v0.w + v1.x + v1.y + v1.z + v1.w;
#pragma unroll
  for (int off = 32; off; off >>= 1) s += __shfl_xor(s, off, 64);
  const float inv = 1.f / s;

  v0.x *= inv; v0.y *= inv; v0.z *= inv; v0.w *= inv;
  v1.x *= inv; v1.y *= inv; v1.z *= inv; v1.w *= inv;
  *(float4*)(p + lane * 4)       = v0;
  *(float4*)(p + 256 + lane * 4) = v1;
}

// ---------------------------------------------------------------------------
extern "C" void kernel_launch(void* const* d_in, const int* in_sizes, int n_in,
                              void* d_out, int out_size, void* d_ws, size_t ws_size,
                              hipStream_t stream) {
  const float* x    = (const float*)d_in[0];   // [B,T,I]
  const float* h0   = (const float*)d_in[1];   // [1,B,H]
  const float* Wih  = (const float*)d_in[2];   // [H,I]
  const float* Whh  = (const float*)d_in[3];   // [H,H]
  const float* bih  = (const float*)d_in[4];   // [H]
  const float* bhh  = (const float*)d_in[5];   // [H]
  const float* Wout = (const float*)d_in[6];   // [O,H]
  const float* bout = (const float*)d_in[7];   // [O]

  float* outp = (float*)d_out;                       // [B,T,O]
  float* z    = (float*)d_out + (size_t)MT * O_;     // [B,T,H]

  static unsigned* cnt = nullptr;
  if (cnt == nullptr) {
    void* p = nullptr;
    hipGetSymbolAddress(&p, HIP_SYMBOL(g_cnt));
    cnt = (unsigned*)p;
  }

  // Phase 1: pre = x @ W_ih^T + b_ih, into z region; zeroes ready flags.
  gemm_nt_bias<<<dim3(MT / 128, H_ / 128), 256, 0, stream>>>(z, x, Wih, bih, MT, H_, I_, cnt);

  // Phase 2: all 512 recurrence steps in one cooperative persistent kernel.
  {
    float* z_a = z; const float* h0_a = h0; const float* Whh_a = Whh;
    const float* bhh_a = bhh; unsigned* cnt_a = cnt;
    void* kargs[] = {&z_a, &h0_a, &Whh_a, &bhh_a, &cnt_a};
    hipLaunchCooperativeKernel((const void*)rnn_fused, dim3(256), dim3(512),
                               kargs, 0, stream);
  }

  // Phase 3: logits = z @ W_out^T + b_out, then row softmax in place
  gemm_nt_bias<<<dim3(MT / 128, O_ / 128), 256, 0, stream>>>(outp, z, Wout, bout, MT, O_, H_, nullptr);
  softmax_rows<<<dim3(MT / 4), 256, 0, stream>>>(outp);
}